// Round 4
// baseline (683.490 us; speedup 1.0000x reference)
//
#include <hip/hip_runtime.h>
#include <hip/hip_bf16.h>

#define NN 2048
#define CC 128
#define CPC 16
#define HH 8
#define DD 16
#define WHALF 64

typedef __hip_bfloat16 bf16;

__device__ __forceinline__ float b2f(bf16 x){ return __bfloat162float(x); }
__device__ __forceinline__ float sigf(float x){ return 1.0f/(1.0f+__expf(-x)); }
// generic input load: inputs may be bf16 or fp32 (runtime-detected flag)
__device__ __forceinline__ float ld(const void* p, size_t i, bool bf){
  return bf ? __bfloat162float(((const bf16*)p)[i]) : ((const float*)p)[i];
}

// mask == 1.0 exactly. bf16 1.0 = 0x3F80 at word 0; fp32 1.0 = [0x0000, 0x3F80].
__global__ void detect_dtype(const void* __restrict__ mask, int* __restrict__ flag){
  const unsigned short* u = (const unsigned short*)mask;
  *flag = (u[0] == 0x3F80) ? 1 : 0;   // 1 = inputs are bf16
}

// LayerNorm per row of [NN][CC]; one wave per row; optionally write raw fp32 copy.
__global__ __launch_bounds__(256) void ln_rows(const void* __restrict__ x,
                                               const int* __restrict__ flag,
                                               float* __restrict__ ln,
                                               float* __restrict__ raw) {
  const bool bf = (*flag != 0);
  int row = blockIdx.x*4 + (threadIdx.x>>6);
  int lane = threadIdx.x & 63;
  size_t base = (size_t)row*CC;
  float v0 = ld(x, base + 2*lane, bf), v1 = ld(x, base + 2*lane + 1, bf);
  float s = v0+v1, sq = v0*v0+v1*v1;
  #pragma unroll
  for (int m=32;m;m>>=1){ s += __shfl_xor(s,m); sq += __shfl_xor(sq,m); }
  float mean = s*(1.0f/CC);
  float var  = sq*(1.0f/CC) - mean*mean;
  float inv  = rsqrtf(var+1e-5f);
  float* lr = ln + base;
  lr[2*lane]   = (v0-mean)*inv;
  lr[2*lane+1] = (v1-mean)*inv;
  if (raw){
    float* rr = raw + base;
    rr[2*lane]=v0; rr[2*lane+1]=v1;
  }
}

// out[N x M] = (A * diag(ascale?)) @ W + bias?, A fp32 [N x K] (workspace), W input [K x M].
// Block: 32 rows x 128 cols; 256 threads; each thread 4 rows x 4 cols.
template<int K>
__global__ __launch_bounds__(256) void gemm_k(const float* __restrict__ A,
                                              const void* __restrict__ ascale,
                                              const void* __restrict__ W,
                                              const void* __restrict__ bias,
                                              const int* __restrict__ flag,
                                              float* __restrict__ out, int M) {
  __shared__ float As[32*K];
  const bool bf = (*flag != 0);
  const int t = threadIdx.x;
  const int row0 = blockIdx.x*32;
  const int colBase = blockIdx.y*128;
  const float* Ab = A + (size_t)row0*K;
  const int count4 = 32*K/4;
  if (ascale){
    for (int idx = t; idx < count4; idx += 256){
      float4 a = ((const float4*)Ab)[idx];
      int k = (idx*4) & (K-1);
      a.x *= ld(ascale,k,bf);   a.y *= ld(ascale,k+1,bf);
      a.z *= ld(ascale,k+2,bf); a.w *= ld(ascale,k+3,bf);
      ((float4*)As)[idx] = a;
    }
  } else {
    for (int idx = t; idx < count4; idx += 256)
      ((float4*)As)[idx] = ((const float4*)Ab)[idx];
  }
  __syncthreads();
  const int tc = t & 31;     // 4 cols each
  const int tr = t >> 5;     // 4 rows each (8 groups * 4 = 32 rows)
  const int col = colBase + tc*4;
  float acc[4][4];
  #pragma unroll
  for (int r=0;r<4;r++)
    #pragma unroll
    for (int c=0;c<4;c++) acc[r][c]=0.0f;
  if (bf){
    const bf16* Wb = (const bf16*)W;
    for (int k=0;k<K;k++){
      union { uint2 u; bf16 h[4]; } wu;
      wu.u = *(const uint2*)(Wb + (size_t)k*M + col);
      float w0=b2f(wu.h[0]), w1=b2f(wu.h[1]), w2=b2f(wu.h[2]), w3=b2f(wu.h[3]);
      #pragma unroll
      for (int r=0;r<4;r++){
        float a = As[(tr*4+r)*K + k];
        acc[r][0] += a*w0; acc[r][1] += a*w1; acc[r][2] += a*w2; acc[r][3] += a*w3;
      }
    }
  } else {
    const float* Wf = (const float*)W;
    for (int k=0;k<K;k++){
      float4 w = *(const float4*)(Wf + (size_t)k*M + col);
      #pragma unroll
      for (int r=0;r<4;r++){
        float a = As[(tr*4+r)*K + k];
        acc[r][0] += a*w.x; acc[r][1] += a*w.y; acc[r][2] += a*w.z; acc[r][3] += a*w.w;
      }
    }
  }
  float b0=0,b1=0,b2=0,b3=0;
  if (bias){ b0=ld(bias,col,bf); b1=ld(bias,col+1,bf); b2=ld(bias,col+2,bf); b3=ld(bias,col+3,bf); }
  #pragma unroll
  for (int r=0;r<4;r++){
    float4 o; o.x=acc[r][0]+b0; o.y=acc[r][1]+b1; o.z=acc[r][2]+b2; o.w=acc[r][3]+b3;
    *(float4*)(out + (size_t)(row0+tr*4+r)*M + col) = o;
  }
}

__global__ void ew_adaln(const float* __restrict__ gbuf, const float* __restrict__ sbuf,
                         const float* __restrict__ lna, float* __restrict__ outp, int n){
  int i = blockIdx.x*256 + threadIdx.x;
  if (i<n) outp[i] = sigf(gbuf[i])*lna[i] + sbuf[i];
}

__global__ void ew_swiglu(float* __restrict__ sw, const float* __restrict__ hd, int n){
  int i = blockIdx.x*256 + threadIdx.x;
  if (i<n){ float x = sw[i]; sw[i] = x*sigf(x)*hd[i]; }
}

// NOTE: output is fp32 (reference returns float32) — round-3 bug was writing bf16 here.
__global__ void ew_final(const float* __restrict__ og, const float* __restrict__ ao,
                         const float* __restrict__ tg, const float* __restrict__ tr,
                         float* __restrict__ outp, int n){
  int i = blockIdx.x*256 + threadIdx.x;
  if (i<n) outp[i] = sigf(og[i])*ao[i] + sigf(tg[i])*tr[i];
}

// Windowed attention with pair bias. One block per query row i. 256 threads.
__global__ __launch_bounds__(256) void attn_win(const float* __restrict__ q,
    const float* __restrict__ k, const float* __restrict__ v,
    const float* __restrict__ g, const void* __restrict__ pair,
    const void* __restrict__ pls, const void* __restrict__ plb,
    const void* __restrict__ w_pair, const void* __restrict__ mask,
    const int* __restrict__ flag, float* __restrict__ o_out) {
  __shared__ float qs[CC];
  __shared__ float sc[HH][132];
  __shared__ float wp[CPC][HH];
  __shared__ float plss[CPC], plbs[CPC];
  __shared__ float inv_sum[HH];
  const bool bf = (*flag != 0);
  const int i = blockIdx.x;
  const int t = threadIdx.x;
  if (t < CC) qs[t] = q[(size_t)i*CC + t] * 0.25f;   // D^-0.5 = 1/4
  if (t < CPC*HH) wp[t>>3][t&7] = ld(w_pair, t, bf); // w_pair [CP][H] row-major
  if (t >= 128 && t < 128+CPC){ plss[t-128]=ld(pls,t-128,bf); plbs[t-128]=ld(plb,t-128,bf); }
  __syncthreads();
  const int jlo = (i-WHALF > 0) ? i-WHALF : 0;
  const int jhi = (i+WHALF < NN-1) ? i+WHALF : NN-1;
  const int nj = jhi - jlo + 1;      // 65..129
  if (t < nj){
    const int j = jlo + t;
    float pv[CPC]; float s=0.f, sq=0.f;
    const size_t pbase = ((size_t)i*NN + j)*CPC;
    #pragma unroll
    for (int c=0;c<CPC;c++){ float x=ld(pair, pbase+c, bf); pv[c]=x; s+=x; sq+=x*x; }
    float mean = s*(1.0f/CPC);
    float var  = sq*(1.0f/CPC)-mean*mean;
    float inv  = rsqrtf(var+1e-5f);
    #pragma unroll
    for (int c=0;c<CPC;c++) pv[c] = (pv[c]-mean)*inv*plss[c] + plbs[c];
    float mterm = 1e9f*(ld(mask,j,bf)-1.0f);
    const float* kr = k + (size_t)j*CC;
    #pragma unroll
    for (int h=0;h<HH;h++){
      float bias = 0.f;
      #pragma unroll
      for (int c=0;c<CPC;c++) bias += pv[c]*wp[c][h];
      float d = 0.f;
      #pragma unroll
      for (int dd=0;dd<DD;dd++) d += qs[h*DD+dd]*kr[h*DD+dd];
      sc[h][t] = d + bias + mterm;
    }
  }
  __syncthreads();
  { // per-head softmax: 8 groups of 32 lanes
    const int h = t >> 5;
    const int l = t & 31;
    float m = -1e30f;
    for (int jj=l; jj<nj; jj+=32) m = fmaxf(m, sc[h][jj]);
    #pragma unroll
    for (int mm=16;mm;mm>>=1) m = fmaxf(m, __shfl_xor(m,mm));
    float ss = 0.f;
    for (int jj=l; jj<nj; jj+=32){ float e=__expf(sc[h][jj]-m); sc[h][jj]=e; ss+=e; }
    #pragma unroll
    for (int mm=16;mm;mm>>=1) ss += __shfl_xor(ss,mm);
    if (l==0) inv_sum[h] = 1.0f/ss;
  }
  __syncthreads();
  if (t < CC){
    const int h = t >> 4;
    float acc = 0.f;
    for (int jj=0; jj<nj; jj++)
      acc += sc[h][jj] * v[(size_t)(jlo+jj)*CC + t];
    float gate = sigf(g[(size_t)i*CC + t]);
    o_out[(size_t)i*CC + t] = acc * inv_sum[h] * gate;
  }
}

extern "C" void kernel_launch(void* const* d_in, const int* in_sizes, int n_in,
                              void* d_out, int out_size, void* d_ws, size_t ws_size,
                              hipStream_t stream) {
  const void* a_in = d_in[0];
  const void* s_in = d_in[1];
  const void* pair = d_in[2];
  const void* mask = d_in[3];
  const void* adaln_s_scale = d_in[4];
  const void* adaln_gate_w  = d_in[5];
  const void* adaln_gate_b  = d_in[6];
  const void* adaln_skip_w  = d_in[7];
  const void* wq = d_in[8];
  const void* wk = d_in[9];
  const void* wv = d_in[10];
  const void* wg = d_in[11];
  const void* bg = d_in[12];
  const void* wo = d_in[13];
  const void* bo = d_in[14];
  const void* pls = d_in[15];
  const void* plb = d_in[16];
  const void* w_pair = d_in[17];
  const void* out_gate_w = d_in[18];
  const void* out_gate_b = d_in[19];
  const void* t_s_scale  = d_in[20];
  const void* t_gate_w   = d_in[21];
  const void* t_gate_b   = d_in[22];
  const void* t_skip_w   = d_in[23];
  const void* t_swish_w  = d_in[24];
  const void* t_hidden_w = d_in[25];
  const void* t_out_w    = d_in[26];
  const void* t_out_gate_w = d_in[27];
  const void* t_out_gate_b = d_in[28];

  // Workspace: [flag: 256 B][9 units x 1 MiB] (liveness-packed; ws_size ~16 MiB)
  int* flag = (int*)d_ws;
  float* ws = (float*)((char*)d_ws + 256);
  const size_t U = (size_t)NN*CC;   // 262144 floats per unit
  float* ln_a  = ws + 0*U;   // U0: dies after adaLN#2 ew
  float* ln_s  = ws + 1*U;   // U1: dies after adaLN gemms
  float* s_f32 = ws + 2*U;   // U2: dies after og/tg gemms (done early)
  float* og    = ws + 3*U;   // U3: live to end
  float* tg    = ws + 4*U;   // U4: live to end
  float* gbuf  = ws + 5*U;   // U5: adaLN gate scratch
  float* sbuf  = ws + 6*U;   // U6: adaLN skip scratch
  float* a_att = ws + 7*U;   // U7: adaLN#1 out; dies after q/k/v/g
  float* tcond = sbuf;       // U6 alias (elementwise-safe)
  float* qb    = ws + 0*U;   // U0 reuse
  float* kb    = ws + 1*U;   // U1 reuse
  float* vb    = ws + 5*U;   // U5 reuse
  float* gg    = ws + 8*U;   // U8
  float* o_gat = ws + 7*U;   // U7 reuse (a_att dead)
  float* aout  = ws + 0*U;   // U0 reuse (qb dead)
  float* swb   = ws + 7*U;   // U7+U8 (o_gat/gg dead)
  float* hdb   = ws + 1*U;   // U1+U2 (kb/s_f32 dead)
  float* trb   = ws + 5*U;   // U5 reuse (vb dead)

  dim3 blk(256);
  detect_dtype<<<1, 1, 0, stream>>>(mask, flag);
  // LayerNorms (shared by both AdaLN blocks); also fp32 copy of s for gates
  ln_rows<<<NN/4, blk, 0, stream>>>(a_in, flag, ln_a, nullptr);
  ln_rows<<<NN/4, blk, 0, stream>>>(s_in, flag, ln_s, s_f32);
  // output gates (pre-sigmoid), from raw s — early so s_f32 dies
  gemm_k<128><<<dim3(NN/32,1), blk, 0, stream>>>(s_f32, nullptr, out_gate_w, out_gate_b, flag, og, 128);
  gemm_k<128><<<dim3(NN/32,1), blk, 0, stream>>>(s_f32, nullptr, t_out_gate_w, t_out_gate_b, flag, tg, 128);
  // AdaLN #1 (attention)
  gemm_k<128><<<dim3(NN/32,1), blk, 0, stream>>>(ln_s, adaln_s_scale, adaln_gate_w, adaln_gate_b, flag, gbuf, 128);
  gemm_k<128><<<dim3(NN/32,1), blk, 0, stream>>>(ln_s, adaln_s_scale, adaln_skip_w, nullptr, flag, sbuf, 128);
  ew_adaln<<<(NN*CC)/256, blk, 0, stream>>>(gbuf, sbuf, ln_a, a_att, NN*CC);
  // AdaLN #2 (transition) — tcond aliases sbuf (elementwise, safe)
  gemm_k<128><<<dim3(NN/32,1), blk, 0, stream>>>(ln_s, t_s_scale, t_gate_w, t_gate_b, flag, gbuf, 128);
  gemm_k<128><<<dim3(NN/32,1), blk, 0, stream>>>(ln_s, t_s_scale, t_skip_w, nullptr, flag, sbuf, 128);
  ew_adaln<<<(NN*CC)/256, blk, 0, stream>>>(gbuf, sbuf, ln_a, tcond, NN*CC);
  // attention projections
  gemm_k<128><<<dim3(NN/32,1), blk, 0, stream>>>(a_att, nullptr, wq, nullptr, flag, qb, 128);
  gemm_k<128><<<dim3(NN/32,1), blk, 0, stream>>>(a_att, nullptr, wk, nullptr, flag, kb, 128);
  gemm_k<128><<<dim3(NN/32,1), blk, 0, stream>>>(a_att, nullptr, wv, nullptr, flag, vb, 128);
  gemm_k<128><<<dim3(NN/32,1), blk, 0, stream>>>(a_att, nullptr, wg, bg, flag, gg, 128);
  // windowed attention -> o_gated (U7)
  attn_win<<<NN, blk, 0, stream>>>(qb, kb, vb, gg, pair, pls, plb, w_pair, mask, flag, o_gat);
  // output projection -> attn_out (U0)
  gemm_k<128><<<dim3(NN/32,1), blk, 0, stream>>>(o_gat, nullptr, wo, bo, flag, aout, 128);
  // transition: SwiGLU
  gemm_k<128><<<dim3(NN/32,2), blk, 0, stream>>>(tcond, nullptr, t_swish_w, nullptr, flag, swb, 256);
  gemm_k<128><<<dim3(NN/32,2), blk, 0, stream>>>(tcond, nullptr, t_hidden_w, nullptr, flag, hdb, 256);
  ew_swiglu<<<(NN*256)/256, blk, 0, stream>>>(swb, hdb, NN*256);
  gemm_k<256><<<dim3(NN/32,1), blk, 0, stream>>>(swb, nullptr, t_out_w, nullptr, flag, trb, 128);
  // final combine -> fp32 out
  ew_final<<<(NN*CC)/256, blk, 0, stream>>>(og, aout, tg, trb, (float*)d_out, NN*CC);
}

// Round 5
// 535.576 us; speedup vs baseline: 1.2762x; 1.2762x over previous
//
#include <hip/hip_runtime.h>

#define NN 2048
#define CC 128
#define CPC 16
#define HH 8
#define DD 16
#define WHALF 64

__device__ __forceinline__ float sigf(float x){ return 1.0f/(1.0f+__expf(-x)); }

// LayerNorm of a (y=0) and s (y=1); one wave per row.
__global__ __launch_bounds__(256) void ln_both(const float* __restrict__ a,
                                               const float* __restrict__ s,
                                               float* __restrict__ ln_a,
                                               float* __restrict__ ln_s){
  const float* x = blockIdx.y ? s : a;
  float* ln = blockIdx.y ? ln_s : ln_a;
  int row = blockIdx.x*4 + (threadIdx.x>>6);
  int lane = threadIdx.x & 63;
  size_t base = (size_t)row*CC;
  float2 v = *(const float2*)(x + base + 2*lane);
  float ssum = v.x+v.y, sq = v.x*v.x+v.y*v.y;
  #pragma unroll
  for (int m=32;m;m>>=1){ ssum += __shfl_xor(ssum,m); sq += __shfl_xor(sq,m); }
  float mean = ssum*(1.0f/CC);
  float var  = sq*(1.0f/CC)-mean*mean;
  float inv  = rsqrtf(var+1e-5f);
  float2 o; o.x=(v.x-mean)*inv; o.y=(v.y-mean)*inv;
  *(float2*)(ln + base + 2*lane) = o;
}

// Core: C[m] = (A*diag(scale)?) @ Wm for up to 2 weight mats sharing A.
// Block covers RPT*8 rows x 128 cols; 256 threads; thread = (tr=t>>5 row slot, tc=t&31 col*4).
template<int K, int RPT, int NM>
__device__ __forceinline__ void gemm_core(const float* __restrict__ Arows,
                                          const float* __restrict__ scale,
                                          const float* __restrict__ W0,
                                          const float* __restrict__ W1,
                                          int ldw, int colBase,
                                          float acc[NM][RPT][4], float* As){
  const int t = threadIdx.x;
  constexpr int ROWS = RPT*8;
  const int nv = ROWS*K/4;
  for (int i=t;i<nv;i+=256){
    float4 v = ((const float4*)Arows)[i];
    if (scale){
      int kk = (i*4)&(K-1);
      v.x*=scale[kk]; v.y*=scale[kk+1]; v.z*=scale[kk+2]; v.w*=scale[kk+3];
    }
    ((float4*)As)[i]=v;
  }
  __syncthreads();
  const int tr = t>>5;
  const int col = colBase + (t&31)*4;
  #pragma unroll
  for(int m=0;m<NM;m++)
    #pragma unroll
    for(int r=0;r<RPT;r++){ acc[m][r][0]=0;acc[m][r][1]=0;acc[m][r][2]=0;acc[m][r][3]=0; }
  #pragma unroll 4
  for (int k=0;k<K;k++){
    float a[RPT];
    #pragma unroll
    for (int r=0;r<RPT;r++) a[r]=As[(tr*RPT+r)*K+k];   // 2-addr broadcast per wave: free
    {
      float4 w = *(const float4*)(W0 + (size_t)k*ldw + col);
      #pragma unroll
      for (int r=0;r<RPT;r++){acc[0][r][0]+=a[r]*w.x;acc[0][r][1]+=a[r]*w.y;acc[0][r][2]+=a[r]*w.z;acc[0][r][3]+=a[r]*w.w;}
    }
    if constexpr (NM>1){
      float4 w = *(const float4*)(W1 + (size_t)k*ldw + col);
      #pragma unroll
      for (int r=0;r<RPT;r++){acc[1][r][0]+=a[r]*w.x;acc[1][r][1]+=a[r]*w.y;acc[1][r][2]+=a[r]*w.z;acc[1][r][3]+=a[r]*w.w;}
    }
  }
}

// sigmoid(s @ W + b) for the two output gates -> sg_og, sg_tg (post-sigmoid).
__global__ __launch_bounds__(256) void k_gates(const float* __restrict__ s,
    const float* __restrict__ W0, const float* __restrict__ b0,
    const float* __restrict__ W1, const float* __restrict__ b1,
    float* __restrict__ sgog, float* __restrict__ sgtg){
  __shared__ float As[8*128];
  float acc[2][1][4];
  const int row0 = blockIdx.x*8;
  gemm_core<128,1,2>(s + (size_t)row0*CC, nullptr, W0, W1, 128, 0, acc, As);
  const int col = (threadIdx.x&31)*4;
  const int row = row0 + (threadIdx.x>>5);
  float4 v0 = *(const float4*)(b0+col);
  float4 v1 = *(const float4*)(b1+col);
  float4 o0, o1;
  o0.x=sigf(acc[0][0][0]+v0.x); o0.y=sigf(acc[0][0][1]+v0.y); o0.z=sigf(acc[0][0][2]+v0.z); o0.w=sigf(acc[0][0][3]+v0.w);
  o1.x=sigf(acc[1][0][0]+v1.x); o1.y=sigf(acc[1][0][1]+v1.y); o1.z=sigf(acc[1][0][2]+v1.z); o1.w=sigf(acc[1][0][3]+v1.w);
  *(float4*)(sgog + (size_t)row*CC + col) = o0;
  *(float4*)(sgtg + (size_t)row*CC + col) = o1;
}

// AdaLN: out = sigmoid(sn@gate_w + gate_b) * ln_a + sn@skip_w, sn = ln_s*scale.
__global__ __launch_bounds__(256) void k_adaln(const float* __restrict__ ln_s,
    const float* __restrict__ sscale,
    const float* __restrict__ gate_w, const float* __restrict__ gate_b,
    const float* __restrict__ skip_w, const float* __restrict__ ln_a,
    float* __restrict__ outp){
  __shared__ float As[8*128];
  float acc[2][1][4];
  const int row0 = blockIdx.x*8;
  gemm_core<128,1,2>(ln_s + (size_t)row0*CC, sscale, gate_w, skip_w, 128, 0, acc, As);
  const int col = (threadIdx.x&31)*4;
  const int row = row0 + (threadIdx.x>>5);
  float4 gb = *(const float4*)(gate_b+col);
  float4 la = *(const float4*)(ln_a + (size_t)row*CC + col);
  float4 o;
  o.x = sigf(acc[0][0][0]+gb.x)*la.x + acc[1][0][0];
  o.y = sigf(acc[0][0][1]+gb.y)*la.y + acc[1][0][1];
  o.z = sigf(acc[0][0][2]+gb.z)*la.z + acc[1][0][2];
  o.w = sigf(acc[0][0][3]+gb.w)*la.w + acc[1][0][3];
  *(float4*)(outp + (size_t)row*CC + col) = o;
}

// q,k (y=0) and v,g (y=1) projections; g gets bias bg (pre-sigmoid store).
__global__ __launch_bounds__(256) void k_qkvg(const float* __restrict__ A,
    const float* __restrict__ wq, const float* __restrict__ wk,
    const float* __restrict__ wv, const float* __restrict__ wg,
    const float* __restrict__ bg,
    float* __restrict__ qb, float* __restrict__ kb,
    float* __restrict__ vb, float* __restrict__ gg){
  __shared__ float As[16*128];
  float acc[2][2][4];
  const int row0 = blockIdx.x*16;
  const int y = blockIdx.y;
  const float* W0 = y ? wv : wq;
  const float* W1 = y ? wg : wk;
  gemm_core<128,2,2>(A + (size_t)row0*CC, nullptr, W0, W1, 128, 0, acc, As);
  const int col = (threadIdx.x&31)*4;
  float* O0 = y ? vb : qb;
  float* O1 = y ? gg : kb;
  float4 b1 = {0,0,0,0};
  if (y) b1 = *(const float4*)(bg+col);
  #pragma unroll
  for (int r=0;r<2;r++){
    const int row = row0 + (threadIdx.x>>5)*2 + r;
    float4 o0 = {acc[0][r][0],acc[0][r][1],acc[0][r][2],acc[0][r][3]};
    float4 o1 = {acc[1][r][0]+b1.x,acc[1][r][1]+b1.y,acc[1][r][2]+b1.z,acc[1][r][3]+b1.w};
    *(float4*)(O0 + (size_t)row*CC + col) = o0;
    *(float4*)(O1 + (size_t)row*CC + col) = o1;
  }
}

// out = o_gat @ wo + bo
__global__ __launch_bounds__(256) void k_wo(const float* __restrict__ A,
    const float* __restrict__ W, const float* __restrict__ b,
    float* __restrict__ outp){
  __shared__ float As[8*128];
  float acc[1][1][4];
  const int row0 = blockIdx.x*8;
  gemm_core<128,1,1>(A + (size_t)row0*CC, nullptr, W, nullptr, 128, 0, acc, As);
  const int col = (threadIdx.x&31)*4;
  const int row = row0 + (threadIdx.x>>5);
  float4 bb = *(const float4*)(b+col);
  float4 o = {acc[0][0][0]+bb.x, acc[0][0][1]+bb.y, acc[0][0][2]+bb.z, acc[0][0][3]+bb.w};
  *(float4*)(outp + (size_t)row*CC + col) = o;
}

// hid[:, y*128+col] = silu(t@swish) * (t@hidden); ldw=256.
__global__ __launch_bounds__(256) void k_swiglu(const float* __restrict__ A,
    const float* __restrict__ sw_w, const float* __restrict__ hd_w,
    float* __restrict__ hid){
  __shared__ float As[8*128];
  float acc[2][1][4];
  const int row0 = blockIdx.x*8;
  const int cb = blockIdx.y*128;
  gemm_core<128,1,2>(A + (size_t)row0*CC, nullptr, sw_w, hd_w, 256, cb, acc, As);
  const int col = cb + (threadIdx.x&31)*4;
  const int row = row0 + (threadIdx.x>>5);
  float4 o;
  o.x = acc[0][0][0]*sigf(acc[0][0][0])*acc[1][0][0];
  o.y = acc[0][0][1]*sigf(acc[0][0][1])*acc[1][0][1];
  o.z = acc[0][0][2]*sigf(acc[0][0][2])*acc[1][0][2];
  o.w = acc[0][0][3]*sigf(acc[0][0][3])*acc[1][0][3];
  *(float4*)(hid + (size_t)row*256 + col) = o;
}

// final: out = sg_og*aout + sg_tg*(hid @ t_out_w); K=256.
__global__ __launch_bounds__(256) void k_tout(const float* __restrict__ hid,
    const float* __restrict__ W,
    const float* __restrict__ sgog, const float* __restrict__ aout,
    const float* __restrict__ sgtg, float* __restrict__ outp){
  __shared__ float As[8*256];
  float acc[1][1][4];
  const int row0 = blockIdx.x*8;
  gemm_core<256,1,1>(hid + (size_t)row0*256, nullptr, W, nullptr, 128, 0, acc, As);
  const int col = (threadIdx.x&31)*4;
  const int row = row0 + (threadIdx.x>>5);
  float4 g0 = *(const float4*)(sgog + (size_t)row*CC + col);
  float4 ao = *(const float4*)(aout + (size_t)row*CC + col);
  float4 g1 = *(const float4*)(sgtg + (size_t)row*CC + col);
  float4 o;
  o.x = g0.x*ao.x + g1.x*acc[0][0][0];
  o.y = g0.y*ao.y + g1.y*acc[0][0][1];
  o.z = g0.z*ao.z + g1.z*acc[0][0][2];
  o.w = g0.w*ao.w + g1.w*acc[0][0][3];
  *(float4*)(outp + (size_t)row*CC + col) = o;
}

// Windowed attention with pair bias. One block per query row i. 256 threads.
__global__ __launch_bounds__(256) void attn_win(const float* __restrict__ q,
    const float* __restrict__ k, const float* __restrict__ v,
    const float* __restrict__ g, const float* __restrict__ pair,
    const float* __restrict__ pls, const float* __restrict__ plb,
    const float* __restrict__ w_pair, const float* __restrict__ mask,
    float* __restrict__ o_out) {
  __shared__ __align__(16) float qs[CC];
  __shared__ float sc[HH][132];
  __shared__ float wp[CPC][HH];
  __shared__ float plss[CPC], plbs[CPC];
  __shared__ float inv_sum[HH];
  const int i = blockIdx.x;
  const int t = threadIdx.x;
  if (t < CC) qs[t] = q[(size_t)i*CC + t] * 0.25f;   // D^-0.5 = 1/4
  if (t < CPC*HH) wp[t>>3][t&7] = w_pair[t];         // [CP][H] row-major
  if (t >= 128 && t < 128+CPC){ plss[t-128]=pls[t-128]; plbs[t-128]=plb[t-128]; }
  __syncthreads();
  const int jlo = (i-WHALF > 0) ? i-WHALF : 0;
  const int jhi = (i+WHALF < NN-1) ? i+WHALF : NN-1;
  const int nj = jhi - jlo + 1;      // 65..129
  if (t < nj){
    const int j = jlo + t;
    float pv[CPC]; float s=0.f, sq=0.f;
    const float4* pp4 = (const float4*)(pair + ((size_t)i*NN + j)*CPC);
    #pragma unroll
    for (int c4=0;c4<CPC/4;c4++){
      float4 x4 = pp4[c4];
      pv[c4*4]=x4.x; pv[c4*4+1]=x4.y; pv[c4*4+2]=x4.z; pv[c4*4+3]=x4.w;
      s += x4.x+x4.y+x4.z+x4.w;
      sq += x4.x*x4.x+x4.y*x4.y+x4.z*x4.z+x4.w*x4.w;
    }
    float mean = s*(1.0f/CPC);
    float var  = sq*(1.0f/CPC)-mean*mean;
    float inv  = rsqrtf(var+1e-5f);
    #pragma unroll
    for (int c=0;c<CPC;c++) pv[c] = (pv[c]-mean)*inv*plss[c] + plbs[c];
    float mterm = 1e9f*(mask[j]-1.0f);
    const float4* kr4 = (const float4*)(k + (size_t)j*CC);
    const float4* qs4 = (const float4*)qs;
    #pragma unroll
    for (int h=0;h<HH;h++){
      float bias = 0.f;
      #pragma unroll
      for (int c=0;c<CPC;c++) bias += pv[c]*wp[c][h];
      float d = 0.f;
      #pragma unroll
      for (int w=0;w<4;w++){
        float4 kk = kr4[h*4+w];
        float4 qq = qs4[h*4+w];
        d += kk.x*qq.x + kk.y*qq.y + kk.z*qq.z + kk.w*qq.w;
      }
      sc[h][t] = d + bias + mterm;
    }
  }
  __syncthreads();
  { // per-head softmax: 8 groups of 32 lanes
    const int h = t >> 5;
    const int l = t & 31;
    float m = -1e30f;
    for (int jj=l; jj<nj; jj+=32) m = fmaxf(m, sc[h][jj]);
    #pragma unroll
    for (int mm=16;mm;mm>>=1) m = fmaxf(m, __shfl_xor(m,mm));
    float ss = 0.f;
    for (int jj=l; jj<nj; jj+=32){ float e=__expf(sc[h][jj]-m); sc[h][jj]=e; ss+=e; }
    #pragma unroll
    for (int mm=16;mm;mm>>=1) ss += __shfl_xor(ss,mm);
    if (l==0) inv_sum[h] = 1.0f/ss;
  }
  __syncthreads();
  if (t < CC){
    const int h = t >> 4;
    float acc = 0.f;
    for (int jj=0; jj<nj; jj++)
      acc += sc[h][jj] * v[(size_t)(jlo+jj)*CC + t];
    float gate = sigf(g[(size_t)i*CC + t]);
    o_out[(size_t)i*CC + t] = acc * inv_sum[h] * gate;
  }
}

extern "C" void kernel_launch(void* const* d_in, const int* in_sizes, int n_in,
                              void* d_out, int out_size, void* d_ws, size_t ws_size,
                              hipStream_t stream) {
  const float* a_in = (const float*)d_in[0];
  const float* s_in = (const float*)d_in[1];
  const float* pair = (const float*)d_in[2];
  const float* mask = (const float*)d_in[3];
  const float* adaln_s_scale = (const float*)d_in[4];
  const float* adaln_gate_w  = (const float*)d_in[5];
  const float* adaln_gate_b  = (const float*)d_in[6];
  const float* adaln_skip_w  = (const float*)d_in[7];
  const float* wq = (const float*)d_in[8];
  const float* wk = (const float*)d_in[9];
  const float* wv = (const float*)d_in[10];
  const float* wg = (const float*)d_in[11];
  const float* bg = (const float*)d_in[12];
  const float* wo = (const float*)d_in[13];
  const float* bo = (const float*)d_in[14];
  const float* pls = (const float*)d_in[15];
  const float* plb = (const float*)d_in[16];
  const float* w_pair = (const float*)d_in[17];
  const float* out_gate_w = (const float*)d_in[18];
  const float* out_gate_b = (const float*)d_in[19];
  const float* t_s_scale  = (const float*)d_in[20];
  const float* t_gate_w   = (const float*)d_in[21];
  const float* t_gate_b   = (const float*)d_in[22];
  const float* t_skip_w   = (const float*)d_in[23];
  const float* t_swish_w  = (const float*)d_in[24];
  const float* t_hidden_w = (const float*)d_in[25];
  const float* t_out_w    = (const float*)d_in[26];
  const float* t_out_gate_w = (const float*)d_in[27];
  const float* t_out_gate_b = (const float*)d_in[28];

  float* ws = (float*)d_ws;
  const size_t U = (size_t)NN*CC;
  float* ln_a  = ws + 0*U;
  float* ln_s  = ws + 1*U;
  float* sg_og = ws + 2*U;
  float* sg_tg = ws + 3*U;
  float* a_att = ws + 4*U;
  float* tcond = ws + 5*U;
  float* qb    = ws + 6*U;
  float* kb    = ws + 7*U;
  float* vb    = ws + 8*U;
  float* gg    = ws + 9*U;
  float* o_gat = ws + 10*U;
  float* aout  = ws + 11*U;
  float* hid   = ws + 12*U;   // 2 units [NN][256]

  dim3 blk(256);
  ln_both<<<dim3(NN/4,2), blk, 0, stream>>>(a_in, s_in, ln_a, ln_s);
  k_gates<<<NN/8, blk, 0, stream>>>(s_in, out_gate_w, out_gate_b, t_out_gate_w, t_out_gate_b, sg_og, sg_tg);
  k_adaln<<<NN/8, blk, 0, stream>>>(ln_s, adaln_s_scale, adaln_gate_w, adaln_gate_b, adaln_skip_w, ln_a, a_att);
  k_adaln<<<NN/8, blk, 0, stream>>>(ln_s, t_s_scale, t_gate_w, t_gate_b, t_skip_w, ln_a, tcond);
  k_qkvg<<<dim3(NN/16,2), blk, 0, stream>>>(a_att, wq, wk, wv, wg, bg, qb, kb, vb, gg);
  attn_win<<<NN, blk, 0, stream>>>(qb, kb, vb, gg, pair, pls, plb, w_pair, mask, o_gat);
  k_wo<<<NN/8, blk, 0, stream>>>(o_gat, wo, bo, aout);
  k_swiglu<<<dim3(NN/8,2), blk, 0, stream>>>(tcond, t_swish_w, t_hidden_w, hid);
  k_tout<<<NN/8, blk, 0, stream>>>(hid, t_out_w, sg_og, aout, sg_tg, (float*)d_out);
}